// Round 6
// baseline (633.432 us; speedup 1.0000x reference)
//
#include <hip/hip_runtime.h>

#define M_DIM 4096
#define K_DIM 4096
#define N_DIM 11008
#define GS 128

typedef _Float16 half8 __attribute__((ext_vector_type(8)));
typedef _Float16 half4 __attribute__((ext_vector_type(4)));
typedef _Float16 half2v __attribute__((ext_vector_type(2)));
typedef float f32x4 __attribute__((ext_vector_type(4)));

#define AH_BYTES 33554432ull              // 4096*4096*2
#define WT_BYTES 90177536ull              // 11008*4096*2

// ================= prepass A: fp32 -> fp16 (linear) =================
__global__ __launch_bounds__(256) void cvtA_kernel(const float4* __restrict__ x4,
                                                   half8* __restrict__ a8) {
    int i = blockIdx.x * 256 + threadIdx.x;
    float4 u = x4[2 * i];
    float4 v = x4[2 * i + 1];
    half8 h;
    h[0] = (_Float16)u.x; h[1] = (_Float16)u.y; h[2] = (_Float16)u.z; h[3] = (_Float16)u.w;
    h[4] = (_Float16)v.x; h[5] = (_Float16)v.y; h[6] = (_Float16)v.z; h[7] = (_Float16)v.w;
    a8[i] = h;
}

// ===== prepass W (v2, LDS-free): thread = 1 qword = 8 k-contig halfs for 1 n =====
// block covers 32 n x 64 k.  reads: 32B-chunked; writes: 128B-chunked.
__global__ __launch_bounds__(256) void dequantW2_kernel(const int* __restrict__ qw,
                                                        const int* __restrict__ qz,
                                                        const float* __restrict__ sc,
                                                        _Float16* __restrict__ Wt) {
    const int b   = blockIdx.x;
    const int nb  = (b % 344) * 32;
    const int kwb = (b / 344) * 8;         // 8 k-words = 64 k
    const int t   = threadIdx.x;
    const int l   = t & 63;
    const int n   = nb + (t >> 6) * 8 + (l >> 3);
    const int kw  = kwb + (l & 7);
    const int g   = kwb >> 4;              // uniform per block (64 | 128)

    float s = sc[(size_t)g * N_DIM + n];
    int zw = qz[(size_t)g * (N_DIM / 8) + (n >> 3)];
    int z  = ((zw >> ((n & 7) * 4)) & 0xF) + 1;
    _Float16 sh  = (_Float16)s;
    _Float16 zsh = (_Float16)(-(float)z * s);
    half2v s2 = {sh, sh}, zs2 = {zsh, zsh};
    const half2v c1024 = {(_Float16)1024.0f, (_Float16)1024.0f};

    unsigned q = (unsigned)qw[(size_t)kw * N_DIM + n];
    half2v p[4];
    #pragma unroll
    for (int jj = 0; jj < 4; ++jj) {
        unsigned tt = ((q >> (4 * jj)) & 0x000F000Fu) | 0x64006400u;
        half2v h = __builtin_bit_cast(half2v, tt);
        h = h - c1024;                     // exact {nib jj, nib jj+4}
        p[jj] = h * s2 + zs2;              // (q - z) * s
    }
    half8 wv;
    wv[0] = p[0][0]; wv[1] = p[1][0]; wv[2] = p[2][0]; wv[3] = p[3][0];
    wv[4] = p[0][1]; wv[5] = p[1][1]; wv[6] = p[2][1]; wv[7] = p[3][1];
    *(half8*)(Wt + (size_t)n * K_DIM + (size_t)kw * 8) = wv;
}

// ======== main GEMM: 256x128 tile, BK=32, 3-buffer ring, 2 blocks/CU ========
// buffer: A 256x32 fp16 (16KB) + B 128x32 fp16 (8KB) = 24KB; x3 = 72KB LDS.
// rows are 64B; swizzle kb ^= ((r>>1)&3)<<4 -> 2-way conflict (free) on frag reads.

#define SWZ(r) ((((r) >> 1) & 3) << 4)

#define VMC3() asm volatile("s_waitcnt vmcnt(3)" ::: "memory")
#define VMC0() asm volatile("s_waitcnt vmcnt(0)" ::: "memory")
#define VMCN()

// stage tile TT (3 x 16B/thread: A rows 0-127, A rows 128-255, B rows 0-127)
#define STAGE3(TT, SB) do {                                                           \
    char* db_ = smem + (SB) * 24576;                                                  \
    __builtin_amdgcn_global_load_lds(                                                 \
        (const __attribute__((address_space(1))) void*)(ahb + srcA0 + (size_t)(TT) * 64), \
        (__attribute__((address_space(3))) void*)(db_ + wid * 1024), 16, 0, 0);       \
    __builtin_amdgcn_global_load_lds(                                                 \
        (const __attribute__((address_space(1))) void*)(ahb + srcA1 + (size_t)(TT) * 64), \
        (__attribute__((address_space(3))) void*)(db_ + 8192 + wid * 1024), 16, 0, 0);\
    __builtin_amdgcn_global_load_lds(                                                 \
        (const __attribute__((address_space(1))) void*)(wtb + srcB0 + (size_t)(TT) * 64), \
        (__attribute__((address_space(3))) void*)(db_ + 16384 + wid * 1024), 16, 0, 0);\
} while (0)

#define BODY(CB, SB, STT, STG, VMC) do {                                              \
    const char* Ab_ = smem + (CB) * 24576;                                            \
    half8 af0 = *(const half8*)(Ab_ + aoff_0);                                        \
    half8 af1 = *(const half8*)(Ab_ + aoff_1);                                        \
    half8 af2 = *(const half8*)(Ab_ + aoff_2);                                        \
    half8 af3 = *(const half8*)(Ab_ + aoff_3);                                        \
    half8 bf0 = *(const half8*)(Ab_ + boff_0);                                        \
    half8 bf1 = *(const half8*)(Ab_ + boff_1);                                        \
    half8 bf2 = *(const half8*)(Ab_ + boff_2);                                        \
    half8 bf3 = *(const half8*)(Ab_ + boff_3);                                        \
    if (STG) { STAGE3((STT), (SB)); }                                                 \
    VMC();                                                                            \
    __builtin_amdgcn_s_barrier();                                                     \
    asm volatile("s_waitcnt lgkmcnt(0)" ::: "memory");                                \
    __builtin_amdgcn_sched_barrier(0);                                                \
    __builtin_amdgcn_s_setprio(1);                                                    \
    acc[0][0] = __builtin_amdgcn_mfma_f32_16x16x32_f16(af0, bf0, acc[0][0], 0, 0, 0); \
    acc[0][1] = __builtin_amdgcn_mfma_f32_16x16x32_f16(af0, bf1, acc[0][1], 0, 0, 0); \
    acc[0][2] = __builtin_amdgcn_mfma_f32_16x16x32_f16(af0, bf2, acc[0][2], 0, 0, 0); \
    acc[0][3] = __builtin_amdgcn_mfma_f32_16x16x32_f16(af0, bf3, acc[0][3], 0, 0, 0); \
    acc[1][0] = __builtin_amdgcn_mfma_f32_16x16x32_f16(af1, bf0, acc[1][0], 0, 0, 0); \
    acc[1][1] = __builtin_amdgcn_mfma_f32_16x16x32_f16(af1, bf1, acc[1][1], 0, 0, 0); \
    acc[1][2] = __builtin_amdgcn_mfma_f32_16x16x32_f16(af1, bf2, acc[1][2], 0, 0, 0); \
    acc[1][3] = __builtin_amdgcn_mfma_f32_16x16x32_f16(af1, bf3, acc[1][3], 0, 0, 0); \
    acc[2][0] = __builtin_amdgcn_mfma_f32_16x16x32_f16(af2, bf0, acc[2][0], 0, 0, 0); \
    acc[2][1] = __builtin_amdgcn_mfma_f32_16x16x32_f16(af2, bf1, acc[2][1], 0, 0, 0); \
    acc[2][2] = __builtin_amdgcn_mfma_f32_16x16x32_f16(af2, bf2, acc[2][2], 0, 0, 0); \
    acc[2][3] = __builtin_amdgcn_mfma_f32_16x16x32_f16(af2, bf3, acc[2][3], 0, 0, 0); \
    acc[3][0] = __builtin_amdgcn_mfma_f32_16x16x32_f16(af3, bf0, acc[3][0], 0, 0, 0); \
    acc[3][1] = __builtin_amdgcn_mfma_f32_16x16x32_f16(af3, bf1, acc[3][1], 0, 0, 0); \
    acc[3][2] = __builtin_amdgcn_mfma_f32_16x16x32_f16(af3, bf2, acc[3][2], 0, 0, 0); \
    acc[3][3] = __builtin_amdgcn_mfma_f32_16x16x32_f16(af3, bf3, acc[3][3], 0, 0, 0); \
    __builtin_amdgcn_s_setprio(0);                                                    \
    __builtin_amdgcn_s_barrier();                                                     \
} while (0)

__global__ __launch_bounds__(512, 4) void gemm9_kernel(
    const _Float16* __restrict__ Ah,   // [M][K] fp16
    const _Float16* __restrict__ Wt,   // [N][K] fp16
    const float* __restrict__ bias,    // [N]
    float* __restrict__ out)           // [M][N] fp32
{
    extern __shared__ char smem[];     // 73728 B

    const int tid  = threadIdx.x;
    const int lane = tid & 63;
    const int wid  = tid >> 6;         // 0..7
    const int wr   = wid >> 1;         // 0..3 (64 rows each)
    const int wc   = wid & 1;          // 0..1 (64 cols each)

    // XCD-aware bijective swizzle: nwg = 16*86 = 1376 = 8*172
    int orig = blockIdx.x;
    int wg = (orig & 7) * 172 + (orig >> 3);
    const int tm = wg / 86;
    const int tn = wg - tm * 86;
    const int m0 = tm * 256;
    const int n0 = tn * 128;

    const char* ahb = (const char*)Ah;
    const char* wtb = (const char*)Wt;

    // ---- staging addresses: row rS = wid*16 + (lane>>2), 4 lanes x 16B per 64B row
    const int rS  = wid * 16 + (lane >> 2);
    const int kbS = ((lane & 3) << 4) ^ SWZ(rS);       // SWZ(rS+128)==SWZ(rS)
    const size_t srcA0 = ((size_t)(m0 + rS) << 13) + kbS;
    const size_t srcA1 = ((size_t)(m0 + rS + 128) << 13) + kbS;
    const size_t srcB0 = ((size_t)(n0 + rS) << 13) + kbS;

    // ---- fragment LDS byte offsets (loop-invariant, swizzled) ----
    const int klane = (lane >> 4) << 4;
    int ra, aoff_0, aoff_1, aoff_2, aoff_3, boff_0, boff_1, boff_2, boff_3;
    ra = wr * 64 +  0 + (lane & 15); aoff_0 = ra * 64 + (klane ^ SWZ(ra));
    ra = wr * 64 + 16 + (lane & 15); aoff_1 = ra * 64 + (klane ^ SWZ(ra));
    ra = wr * 64 + 32 + (lane & 15); aoff_2 = ra * 64 + (klane ^ SWZ(ra));
    ra = wr * 64 + 48 + (lane & 15); aoff_3 = ra * 64 + (klane ^ SWZ(ra));
    ra = wc * 64 +  0 + (lane & 15); boff_0 = 16384 + ra * 64 + (klane ^ SWZ(ra));
    ra = wc * 64 + 16 + (lane & 15); boff_1 = 16384 + ra * 64 + (klane ^ SWZ(ra));
    ra = wc * 64 + 32 + (lane & 15); boff_2 = 16384 + ra * 64 + (klane ^ SWZ(ra));
    ra = wc * 64 + 48 + (lane & 15); boff_3 = 16384 + ra * 64 + (klane ^ SWZ(ra));

    f32x4 acc[4][4];
    #pragma unroll
    for (int i = 0; i < 4; ++i)
        #pragma unroll
        for (int j = 0; j < 4; ++j)
            acc[i][j] = f32x4{0.f, 0.f, 0.f, 0.f};

    // ---- prologue: stage tiles 0,1; confirm tile 0 ----
    STAGE3(0, 0);
    STAGE3(1, 1);
    VMC3();
    __builtin_amdgcn_s_barrier();

    // ---- main loop: T = 0..125, stage T+2, counted vmcnt(3) drains T+1 ----
    for (int it = 0; it < 42; ++it) {
        const int T = 3 * it;
        BODY(0, 2, T + 2, 1, VMC3);
        BODY(1, 0, T + 3, 1, VMC3);
        BODY(2, 1, T + 4, 1, VMC3);
    }
    // ---- peel: tiles 126 (drain 127), 127 ----
    BODY(0, 2, 0, 0, VMC0);
    BODY(1, 0, 0, 0, VMCN);

    // ---- epilogue: + bias, fp32 store (write pattern ideal per r4 WRITE_SIZE) ----
    const int row_base = m0 + wr * 64 + ((lane >> 4) << 2);
    const int col_base = n0 + wc * 64 + (lane & 15);
    #pragma unroll
    for (int ni = 0; ni < 4; ++ni) {
        const int col = col_base + ni * 16;
        const float bv = bias[col];
        #pragma unroll
        for (int mi = 0; mi < 4; ++mi) {
            const int row = row_base + mi * 16;
            #pragma unroll
            for (int j = 0; j < 4; ++j)
                out[(size_t)(row + j) * N_DIM + col] = acc[mi][ni][j] + bv;
        }
    }
}

// ================= fallback (round-2 kernel, used if ws too small) =================
__global__ __launch_bounds__(256, 2) void gptq_fallback_kernel(
    const float* __restrict__ x, const int* __restrict__ qw, const int* __restrict__ qz,
    const float* __restrict__ sc, const float* __restrict__ bias, float* __restrict__ out)
{
    __shared__ _Float16 As[128 * 64];
    __shared__ _Float16 Bs[128 * 64];
    const int tid = threadIdx.x, lane = tid & 63, wid = tid >> 6;
    const int wr = wid >> 1, wc = wid & 1;
    int orig = blockIdx.x;
    int wg = (orig & 7) * 344 + (orig >> 3);
    const int tm = wg / 86, tn = wg - tm * 86;
    const int m0 = tm * 128, n0 = tn * 128;
    const int a_r0 = tid >> 4, a_c4 = tid & 15;
    const int b_nl = tid & 127, b_qr0 = tid >> 7, b_n = n0 + b_nl;
    const float* xg = x + (size_t)(m0 + a_r0) * K_DIM + a_c4 * 4;
    const int* qwg = qw + (size_t)b_qr0 * N_DIM + b_n;
    float4 areg[8]; int breg[4]; float s_cur, zs_cur;
    #pragma unroll
    for (int i = 0; i < 8; ++i) areg[i] = *(const float4*)(xg + (size_t)i * 16 * K_DIM);
    #pragma unroll
    for (int i = 0; i < 4; ++i) breg[i] = qwg[(size_t)i * 2 * N_DIM];
    { int zw = qz[(size_t)(b_n >> 3)]; int z = ((zw >> ((b_n & 7) * 4)) & 0xF) + 1;
      float s = sc[b_n]; s_cur = s; zs_cur = -(float)z * s; }
    f32x4 acc[4][4];
    #pragma unroll
    for (int i = 0; i < 4; ++i)
        #pragma unroll
        for (int j = 0; j < 4; ++j) acc[i][j] = f32x4{0.f,0.f,0.f,0.f};
    const half2v c1024 = {(_Float16)1024.0f, (_Float16)1024.0f};
    for (int kt = 0; kt < 64; ++kt) {
        if (kt) __syncthreads();
        #pragma unroll
        for (int i = 0; i < 8; ++i) {
            int r = i * 16 + a_r0;
            half4 hv; hv[0]=(_Float16)areg[i].x; hv[1]=(_Float16)areg[i].y;
            hv[2]=(_Float16)areg[i].z; hv[3]=(_Float16)areg[i].w;
            int boff = ((r * 64 + a_c4 * 4) * 2) ^ ((r & 7) << 4);
            *(half4*)((char*)As + boff) = hv;
        }
        { _Float16 sh=(_Float16)s_cur, zsh=(_Float16)zs_cur;
          half2v s2={sh,sh}, zs2={zsh,zsh};
          #pragma unroll
          for (int i = 0; i < 4; ++i) {
            unsigned q = (unsigned)breg[i]; half2v p[4];
            #pragma unroll
            for (int j = 0; j < 4; ++j) {
                unsigned t = ((q >> (4*j)) & 0x000F000Fu) | 0x64006400u;
                half2v h = __builtin_bit_cast(half2v, t); h = h - c1024;
                p[j] = h * s2 + zs2;
            }
            half8 wv; wv[0]=p[0][0]; wv[1]=p[1][0]; wv[2]=p[2][0]; wv[3]=p[3][0];
            wv[4]=p[0][1]; wv[5]=p[1][1]; wv[6]=p[2][1]; wv[7]=p[3][1];
            int qr = b_qr0 + i * 2;
            int boff = ((b_nl * 64 + qr * 8) * 2) ^ ((b_nl & 7) << 4);
            *(half8*)((char*)Bs + boff) = wv;
          } }
        __syncthreads();
        if (kt + 1 < 64) {
            const float* xg2 = xg + (size_t)(kt + 1) * 64;
            #pragma unroll
            for (int i = 0; i < 8; ++i) areg[i] = *(const float4*)(xg2 + (size_t)i * 16 * K_DIM);
            const int* qwg2 = qwg + (size_t)(kt + 1) * 8 * N_DIM;
            #pragma unroll
            for (int i = 0; i < 4; ++i) breg[i] = qwg2[(size_t)i * 2 * N_DIM];
            int g = ((kt + 1) * 64) / GS;
            int zw = qz[(size_t)g * (N_DIM / 8) + (b_n >> 3)];
            int z = ((zw >> ((b_n & 7) * 4)) & 0xF) + 1;
            float s = sc[(size_t)g * N_DIM + b_n];
            s_cur = s; zs_cur = -(float)z * s;
        }
        #pragma unroll
        for (int ks = 0; ks < 2; ++ks) {
            half8 af[4], bf[4];
            int kb = ks * 64 + ((lane >> 4) * 16);
            #pragma unroll
            for (int mi = 0; mi < 4; ++mi) {
                int r = wr * 64 + mi * 16 + (lane & 15);
                int boff = (r * 128 + kb) ^ ((r & 7) << 4);
                af[mi] = *(const half8*)((const char*)As + boff);
            }
            #pragma unroll
            for (int ni = 0; ni < 4; ++ni) {
                int c = wc * 64 + ni * 16 + (lane & 15);
                int boff = (c * 128 + kb) ^ ((c & 7) << 4);
                bf[ni] = *(const half8*)((const char*)Bs + boff);
            }
            #pragma unroll
            for (int mi = 0; mi < 4; ++mi)
                #pragma unroll
                for (int ni = 0; ni < 4; ++ni)
                    acc[mi][ni] = __builtin_amdgcn_mfma_f32_16x16x32_f16(af[mi], bf[ni], acc[mi][ni], 0, 0, 0);
        }
    }
    const int col_base = n0 + wc * 64 + (lane & 15);
    const int row_base = m0 + wr * 64 + ((lane >> 4) << 2);
    #pragma unroll
    for (int ni = 0; ni < 4; ++ni) {
        int col = col_base + ni * 16;
        float bv = bias[col];
        #pragma unroll
        for (int mi = 0; mi < 4; ++mi) {
            int row = row_base + mi * 16;
            #pragma unroll
            for (int j = 0; j < 4; ++j)
                out[(size_t)(row + j) * N_DIM + col] = acc[mi][ni][j] + bv;
        }
    }
}

extern "C" void kernel_launch(void* const* d_in, const int* in_sizes, int n_in,
                              void* d_out, int out_size, void* d_ws, size_t ws_size,
                              hipStream_t stream) {
    const float* x    = (const float*)d_in[0];
    const int*   qw   = (const int*)d_in[1];
    const int*   qz   = (const int*)d_in[2];
    const float* sc   = (const float*)d_in[3];
    const float* bias = (const float*)d_in[5];
    float* out = (float*)d_out;

    if (ws_size >= AH_BYTES + WT_BYTES) {
        _Float16* Ah = (_Float16*)d_ws;
        _Float16* Wt = (_Float16*)((char*)d_ws + AH_BYTES);
        cvtA_kernel<<<8192, 256, 0, stream>>>((const float4*)x, (half8*)Ah);
        dequantW2_kernel<<<344 * 64, 256, 0, stream>>>(qw, qz, sc, Wt);
        (void)hipFuncSetAttribute((const void*)gemm9_kernel,
                                  hipFuncAttributeMaxDynamicSharedMemorySize, 73728);
        gemm9_kernel<<<1376, 512, 73728, stream>>>(Ah, Wt, bias, out);
    } else {
        gptq_fallback_kernel<<<2752, 256, 0, stream>>>(x, qw, qz, sc, bias, out);
    }
}

// Round 7
// 597.175 us; speedup vs baseline: 1.0607x; 1.0607x over previous
//
#include <hip/hip_runtime.h>

#define M_DIM 4096
#define K_DIM 4096
#define N_DIM 11008
#define GS 128
#define NKT 64            // K-tiles of 64

typedef _Float16 half8 __attribute__((ext_vector_type(8)));
typedef _Float16 half2v __attribute__((ext_vector_type(2)));
typedef float f32x4 __attribute__((ext_vector_type(4)));

#define AH_BYTES 33554432ull              // 4096*4096*2
#define WT_BYTES 90177536ull              // 11008*4096*2

#define AS1 __attribute__((address_space(1)))
#define AS3 __attribute__((address_space(3)))

// ================= prepass A: fp32 -> fp16 (linear) =================
__global__ __launch_bounds__(256) void cvtA_kernel(const float4* __restrict__ x4,
                                                   half8* __restrict__ a8) {
    int i = blockIdx.x * 256 + threadIdx.x;
    float4 u = x4[2 * i];
    float4 v = x4[2 * i + 1];
    half8 h;
    h[0] = (_Float16)u.x; h[1] = (_Float16)u.y; h[2] = (_Float16)u.z; h[3] = (_Float16)u.w;
    h[4] = (_Float16)v.x; h[5] = (_Float16)v.y; h[6] = (_Float16)v.z; h[7] = (_Float16)v.w;
    a8[i] = h;
}

// ===== prepass W (LDS-free): thread = 1 qword = 8 k-contig halfs for 1 n =====
__global__ __launch_bounds__(256) void dequantW2_kernel(const int* __restrict__ qw,
                                                        const int* __restrict__ qz,
                                                        const float* __restrict__ sc,
                                                        _Float16* __restrict__ Wt) {
    const int b   = blockIdx.x;
    const int nb  = (b % 344) * 32;
    const int kwb = (b / 344) * 8;         // 8 k-words = 64 k
    const int t   = threadIdx.x;
    const int l   = t & 63;
    const int n   = nb + (t >> 6) * 8 + (l >> 3);
    const int kw  = kwb + (l & 7);
    const int g   = kwb >> 4;              // uniform per block

    float s = sc[(size_t)g * N_DIM + n];
    int zw = qz[(size_t)g * (N_DIM / 8) + (n >> 3)];
    int z  = ((zw >> ((n & 7) * 4)) & 0xF) + 1;
    _Float16 sh  = (_Float16)s;
    _Float16 zsh = (_Float16)(-(float)z * s);
    half2v s2 = {sh, sh}, zs2 = {zsh, zsh};
    const half2v c1024 = {(_Float16)1024.0f, (_Float16)1024.0f};

    unsigned q = (unsigned)qw[(size_t)kw * N_DIM + n];
    half2v p[4];
    #pragma unroll
    for (int jj = 0; jj < 4; ++jj) {
        unsigned tt = ((q >> (4 * jj)) & 0x000F000Fu) | 0x64006400u;
        half2v h = __builtin_bit_cast(half2v, tt);
        h = h - c1024;
        p[jj] = h * s2 + zs2;
    }
    half8 wv;
    wv[0] = p[0][0]; wv[1] = p[1][0]; wv[2] = p[2][0]; wv[3] = p[3][0];
    wv[4] = p[0][1]; wv[5] = p[1][1]; wv[6] = p[2][1]; wv[7] = p[3][1];
    *(half8*)(Wt + (size_t)n * K_DIM + (size_t)kw * 8) = wv;
}

// ======== main GEMM (m201 geometry): 256x256, BK=64, 8 waves, 2x64KB dbuf ========
// Buffer b at b*65536: A [256r][64k] at +0 (32KB), B [256c][64k] at +32768.
// Half-tiles (16KB stage units): A0=+0, A1=+16384, B0=+32768, B1=+49152.
// Rows 128B; swizzle: 16B-slot s stored at s ^ (row&7); frag-read key = lane&7.

#define BAR()   __builtin_amdgcn_s_barrier()
#define LGKM0() do { asm volatile("s_waitcnt lgkmcnt(0)" ::: "memory"); \
                     __builtin_amdgcn_sched_barrier(0); } while (0)
#define VMC4()  asm volatile("s_waitcnt vmcnt(4)" ::: "memory")
#define VMC0()  asm volatile("s_waitcnt vmcnt(0)" ::: "memory")
#define VMCN()

#define LDA(cb, MH) \
    _Pragma("unroll") \
    for (int mi = 0; mi < 4; ++mi) { \
        aF[mi][0] = *(const half8*)(smem + (cb)*65536 + arow + (MH)*8192 + mi*2048 + koff0); \
        aF[mi][1] = *(const half8*)(smem + (cb)*65536 + arow + (MH)*8192 + mi*2048 + koff1); \
    }

#define LDB(cb, NH, BF) \
    _Pragma("unroll") \
    for (int ni = 0; ni < 2; ++ni) { \
        BF[ni][0] = *(const half8*)(smem + (cb)*65536 + brow + (NH)*4096 + ni*2048 + koff0); \
        BF[ni][1] = *(const half8*)(smem + (cb)*65536 + brow + (NH)*4096 + ni*2048 + koff1); \
    }

#define MM(MB, NB, BF) \
    _Pragma("unroll") \
    for (int kh = 0; kh < 2; ++kh) \
    _Pragma("unroll") \
    for (int mi = 0; mi < 4; ++mi) \
    _Pragma("unroll") \
    for (int ni = 0; ni < 2; ++ni) \
        acc[(MB)+mi][(NB)+ni] = __builtin_amdgcn_mfma_f32_16x16x32_f16( \
            aF[mi][kh], BF[ni][kh], acc[(MB)+mi][(NB)+ni], 0, 0, 0)

// stage one 16KB half-tile of K-tile T: 2 x 16B per thread (rows j*64+(tid>>3))
#define STAGE_HT(OB, HT, BASE, T) do { \
    __builtin_amdgcn_global_load_lds((const AS1 void*)((BASE) + (size_t)(T)*128), \
        (AS3 void*)(smem + (OB)*65536 + (HT)*16384 + tid*16), 16, 0, 0); \
    __builtin_amdgcn_global_load_lds((const AS1 void*)((BASE) + (size_t)(T)*128 + 524288), \
        (AS3 void*)(smem + (OB)*65536 + (HT)*16384 + 8192 + tid*16), 16, 0, 0); \
} while (0)

// 4 phases per K-tile T (cb = T&1):
//  P0: read A(m0)+B(n0); stage A1(T+1)->cb^1;          MFMA acc[0..3][0..1]
//  P1: read B(n1);       stage B1(T+1)->cb^1;          MFMA acc[0..3][2..3]
//  P2: read A(m1);       stage B0(T+2)->cb;            MFMA acc[4..7][2..3]
//  P3: (no reads);       stage A0(T+2)->cb; vmcnt(4);  MFMA acc[4..7][0..1]
#define TILE(cb, T, S01, S23, VMC) do {                                   \
    LDA(cb, 0); LDB(cb, 0, bF0);                                          \
    if (S01) STAGE_HT((cb)^1, 1, pA1, (T)+1);                             \
    BAR(); LGKM0();                                                       \
    __builtin_amdgcn_s_setprio(1); MM(0, 0, bF0);                         \
    __builtin_amdgcn_s_setprio(0); BAR();                                 \
    LDB(cb, 1, bF1);                                                      \
    if (S01) STAGE_HT((cb)^1, 3, pB1, (T)+1);                             \
    BAR(); LGKM0();                                                       \
    __builtin_amdgcn_s_setprio(1); MM(0, 2, bF1);                         \
    __builtin_amdgcn_s_setprio(0); BAR();                                 \
    LDA(cb, 1);                                                           \
    if (S23) STAGE_HT((cb), 2, pB0, (T)+2);                               \
    BAR(); LGKM0();                                                       \
    __builtin_amdgcn_s_setprio(1); MM(4, 2, bF1);                         \
    __builtin_amdgcn_s_setprio(0); BAR();                                 \
    if (S23) STAGE_HT((cb), 0, pA0, (T)+2);                               \
    VMC();                                                                \
    BAR();                                                                \
    __builtin_amdgcn_s_setprio(1); MM(4, 0, bF0);                         \
    __builtin_amdgcn_s_setprio(0); BAR();                                 \
} while (0)

__global__ __launch_bounds__(512, 2) void gemm10_kernel(
    const _Float16* __restrict__ Ah,   // [M][K] fp16
    const _Float16* __restrict__ Wt,   // [N][K] fp16
    const float* __restrict__ bias,    // [N]
    float* __restrict__ out)           // [M][N] fp32
{
    extern __shared__ char smem[];     // 131072 B

    const int tid  = threadIdx.x;
    const int lane = tid & 63;
    const int wid  = tid >> 6;         // 0..7
    const int wr   = wid >> 2;         // 0..1: 128 rows
    const int wc   = wid & 3;          // 0..3: 64 cols

    // XCD-aware bijective swizzle: nwg = 16*43 = 688 = 8*86
    int orig = blockIdx.x;
    int wg = (orig & 7) * 86 + (orig >> 3);
    const int tm = wg / 43;
    const int tn = wg - tm * 43;
    const int m0 = tm * 256;
    const int n0 = tn * 256;

    // ---- frag-read components (swizzle key = lane&7 for every frag read) ----
    const int koff0 = 16 * (((lane >> 4) + 0) ^ (lane & 7));
    const int koff1 = 16 * (((lane >> 4) + 4) ^ (lane & 7));
    const int arow  = (wr * 128 + (lane & 15)) * 128;
    const int brow  = 32768 + (wc * 64 + (lane & 15)) * 128;

    // ---- staging source (inverse-swizzled global): 8 thr/row, key=(tid>>3)&7 ----
    const int sb = ((tid & 7) * 16) ^ (((tid >> 3) & 7) << 4);
    const char* pA0 = (const char*)Ah + (size_t)(m0 + (tid >> 3)) * 8192 + sb;
    const char* pA1 = pA0 + 1048576;   // +128 rows
    const char* pB0 = (const char*)Wt + (size_t)(n0 + (tid >> 3)) * 8192 + sb;
    const char* pB1 = pB0 + 1048576;

    half8 aF[4][2], bF0[2][2], bF1[2][2];
    f32x4 acc[8][4];
    #pragma unroll
    for (int i = 0; i < 8; ++i)
        #pragma unroll
        for (int j = 0; j < 4; ++j)
            acc[i][j] = f32x4{0.f, 0.f, 0.f, 0.f};

    // ---- prologue: tile0 fully + B0(1),A0(1); confirm tile0 (vmcnt 4) ----
    STAGE_HT(0, 0, pA0, 0);
    STAGE_HT(0, 1, pA1, 0);
    STAGE_HT(0, 2, pB0, 0);
    STAGE_HT(0, 3, pB1, 0);
    STAGE_HT(1, 2, pB0, 1);
    STAGE_HT(1, 0, pA0, 1);
    VMC4();
    BAR();

    // ---- main loop: tiles 0..61 steady-state ----
    for (int t2 = 0; t2 < 31; ++t2) {
        const int T = 2 * t2;
        TILE(0, T,     1, 1, VMC4);
        TILE(1, T + 1, 1, 1, VMC4);
    }
    // ---- tile 62: finish staging tile 63, drain; tile 63: compute only ----
    TILE(0, 62, 1, 0, VMC0);
    TILE(1, 63, 0, 0, VMCN);

    // ---- epilogue: + bias, fp32 store ----
    const int row_base = m0 + wr * 128 + ((lane >> 4) << 2);
    const int col_base = n0 + wc * 64 + (lane & 15);
    #pragma unroll
    for (int ni = 0; ni < 4; ++ni) {
        const int col = col_base + ni * 16;
        const float bv = bias[col];
        #pragma unroll
        for (int mi = 0; mi < 8; ++mi) {
            const int row = row_base + mi * 16;
            #pragma unroll
            for (int j = 0; j < 4; ++j)
                out[(size_t)(row + j) * N_DIM + col] = acc[mi][ni][j] + bv;
        }
    }
}

// ================= fallback (round-2 kernel, used if ws too small) =================
__global__ __launch_bounds__(256, 2) void gptq_fallback_kernel(
    const float* __restrict__ x, const int* __restrict__ qw, const int* __restrict__ qz,
    const float* __restrict__ sc, const float* __restrict__ bias, float* __restrict__ out)
{
    __shared__ _Float16 As[128 * 64];
    __shared__ _Float16 Bs[128 * 64];
    const int tid = threadIdx.x, lane = tid & 63, wid = tid >> 6;
    const int wr = wid >> 1, wc = wid & 1;
    int orig = blockIdx.x;
    int wg = (orig & 7) * 344 + (orig >> 3);
    const int tm = wg / 86, tn = wg - tm * 86;
    const int m0 = tm * 128, n0 = tn * 128;
    const int a_r0 = tid >> 4, a_c4 = tid & 15;
    const int b_nl = tid & 127, b_qr0 = tid >> 7, b_n = n0 + b_nl;
    const float* xg = x + (size_t)(m0 + a_r0) * K_DIM + a_c4 * 4;
    const int* qwg = qw + (size_t)b_qr0 * N_DIM + b_n;
    float4 areg[8]; int breg[4]; float s_cur, zs_cur;
    #pragma unroll
    for (int i = 0; i < 8; ++i) areg[i] = *(const float4*)(xg + (size_t)i * 16 * K_DIM);
    #pragma unroll
    for (int i = 0; i < 4; ++i) breg[i] = qwg[(size_t)i * 2 * N_DIM];
    { int zw = qz[(size_t)(b_n >> 3)]; int z = ((zw >> ((b_n & 7) * 4)) & 0xF) + 1;
      float s = sc[b_n]; s_cur = s; zs_cur = -(float)z * s; }
    f32x4 acc[4][4];
    #pragma unroll
    for (int i = 0; i < 4; ++i)
        #pragma unroll
        for (int j = 0; j < 4; ++j) acc[i][j] = f32x4{0.f,0.f,0.f,0.f};
    const half2v c1024 = {(_Float16)1024.0f, (_Float16)1024.0f};
    for (int kt = 0; kt < 64; ++kt) {
        if (kt) __syncthreads();
        #pragma unroll
        for (int i = 0; i < 8; ++i) {
            int r = i * 16 + a_r0;
            half2v hv0, hv1;
            hv0[0]=(_Float16)areg[i].x; hv0[1]=(_Float16)areg[i].y;
            hv1[0]=(_Float16)areg[i].z; hv1[1]=(_Float16)areg[i].w;
            int boff = ((r * 64 + a_c4 * 4) * 2) ^ ((r & 7) << 4);
            *(half2v*)((char*)As + boff) = hv0;
            *(half2v*)((char*)As + boff + 4) = hv1;
        }
        { _Float16 sh=(_Float16)s_cur, zsh=(_Float16)zs_cur;
          half2v s2={sh,sh}, zs2={zsh,zsh};
          #pragma unroll
          for (int i = 0; i < 4; ++i) {
            unsigned q = (unsigned)breg[i]; half2v p[4];
            #pragma unroll
            for (int j = 0; j < 4; ++j) {
                unsigned t = ((q >> (4*j)) & 0x000F000Fu) | 0x64006400u;
                half2v h = __builtin_bit_cast(half2v, t); h = h - c1024;
                p[j] = h * s2 + zs2;
            }
            half8 wv; wv[0]=p[0][0]; wv[1]=p[1][0]; wv[2]=p[2][0]; wv[3]=p[3][0];
            wv[4]=p[0][1]; wv[5]=p[1][1]; wv[6]=p[2][1]; wv[7]=p[3][1];
            int qr = b_qr0 + i * 2;
            int boff = ((b_nl * 64 + qr * 8) * 2) ^ ((b_nl & 7) << 4);
            *(half8*)((char*)Bs + boff) = wv;
          } }
        __syncthreads();
        if (kt + 1 < 64) {
            const float* xg2 = xg + (size_t)(kt + 1) * 64;
            #pragma unroll
            for (int i = 0; i < 8; ++i) areg[i] = *(const float4*)(xg2 + (size_t)i * 16 * K_DIM);
            const int* qwg2 = qwg + (size_t)(kt + 1) * 8 * N_DIM;
            #pragma unroll
            for (int i = 0; i < 4; ++i) breg[i] = qwg2[(size_t)i * 2 * N_DIM];
            int g = ((kt + 1) * 64) / GS;
            int zw = qz[(size_t)g * (N_DIM / 8) + (b_n >> 3)];
            int z = ((zw >> ((b_n & 7) * 4)) & 0xF) + 1;
            float s = sc[(size_t)g * N_DIM + b_n];
            s_cur = s; zs_cur = -(float)z * s;
        }
        #pragma unroll
        for (int ks = 0; ks < 2; ++ks) {
            half8 af[4], bf[4];
            int kb = ks * 64 + ((lane >> 4) * 16);
            #pragma unroll
            for (int mi = 0; mi < 4; ++mi) {
                int r = wr * 64 + mi * 16 + (lane & 15);
                int boff = (r * 128 + kb) ^ ((r & 7) << 4);
                af[mi] = *(const half8*)((const char*)As + boff);
            }
            #pragma unroll
            for (int ni = 0; ni < 4; ++ni) {
                int c = wc * 64 + ni * 16 + (lane & 15);
                int boff = (c * 128 + kb) ^ ((c & 7) << 4);
                bf[ni] = *(const half8*)((const char*)Bs + boff);
            }
            #pragma unroll
            for (int mi = 0; mi < 4; ++mi)
                #pragma unroll
                for (int ni = 0; ni < 4; ++ni)
                    acc[mi][ni] = __builtin_amdgcn_mfma_f32_16x16x32_f16(af[mi], bf[ni], acc[mi][ni], 0, 0, 0);
        }
    }
    const int col_base = n0 + wc * 64 + (lane & 15);
    const int row_base = m0 + wr * 64 + ((lane >> 4) << 2);
    #pragma unroll
    for (int ni = 0; ni < 4; ++ni) {
        int col = col_base + ni * 16;
        float bv = bias[col];
        #pragma unroll
        for (int mi = 0; mi < 4; ++mi) {
            int row = row_base + mi * 16;
            #pragma unroll
            for (int j = 0; j < 4; ++j)
                out[(size_t)(row + j) * N_DIM + col] = acc[mi][ni][j] + bv;
        }
    }
}

extern "C" void kernel_launch(void* const* d_in, const int* in_sizes, int n_in,
                              void* d_out, int out_size, void* d_ws, size_t ws_size,
                              hipStream_t stream) {
    const float* x    = (const float*)d_in[0];
    const int*   qw   = (const int*)d_in[1];
    const int*   qz   = (const int*)d_in[2];
    const float* sc   = (const float*)d_in[3];
    const float* bias = (const float*)d_in[5];
    float* out = (float*)d_out;

    if (ws_size >= AH_BYTES + WT_BYTES) {
        _Float16* Ah = (_Float16*)d_ws;
        _Float16* Wt = (_Float16*)((char*)d_ws + AH_BYTES);
        cvtA_kernel<<<8192, 256, 0, stream>>>((const float4*)x, (half8*)Ah);
        dequantW2_kernel<<<344 * 64, 256, 0, stream>>>(qw, qz, sc, Wt);
        (void)hipFuncSetAttribute((const void*)gemm10_kernel,
                                  hipFuncAttributeMaxDynamicSharedMemorySize, 131072);
        gemm10_kernel<<<688, 512, 131072, stream>>>(Ah, Wt, bias, out);
    } else {
        gptq_fallback_kernel<<<2752, 256, 0, stream>>>(x, qw, qz, sc, bias, out);
    }
}